// Round 2
// baseline (237.825 us; speedup 1.0000x reference)
//
#include <hip/hip_runtime.h>
#include <math.h>

// Biquad highpass IIR over [B=128, C=2, T=65536] f32.
// R6: fix R5's two regressions, keep its insights.
//   (1) Write granularity: empirical HBM write granule is 512B (R3: 128B
//       pieces -> 1.55x, R5: 256B pieces -> 1.99x, R4: 1KB-contiguous -> 1x).
//       Stores here are 8 x 1KB-contiguous instructions per wave covering an
//       aligned 8KB region => full granule coverage, 1x write traffic.
//   (2) Occupancy: R5's 4 waves/CU starved latency hiding (43% BW, 5.7%
//       VALUBusy). L_CHUNK 64->32 with TS=16 shrinks the live-output
//       constraint to two 4KB tiles => LDS 8KB/wave => 20 waves/CU resident
//       (2x R4's 10). 8192 single-wave blocks.
// Cost: warm ratio (32+64)/32 = 3x raw reads -- strided re-reads absorbed by
// L2/LLC (R5 proved FETCH stays ~compulsory), VALU has 10x headroom.
// LDS layout: slot s = l*4 + m holds row l's logical float4 #((m-(l>>1))&3);
// compute reads at m=(g+(l>>1))&3 give 8 consecutive lanes all 8 bank-quads
// (conflict-free ds_read_b128). DMA source permutation j=((lane&3)-(lane>>3))&3
// keeps each global_load_lds instruction coalesced (16 x 64B segments).
// Numerics: W=64 zero-state warm-up (pole radius 0.8234 => boundary error
// ~4e-6); absmax floor 0.0156 = f32 contraction noise, proven R1-R5.

#define T_LEN    65536
#define L_CHUNK  32
#define W_WARM   64
#define TS       16
#define BLK      64                  // one wave per block
#define ROWS     64                  // chunks per wave (one per lane)
#define BUF_F    (ROWS * TS)         // 1024 floats = 4 KiB per buffer
#define BLOCKS_PER_CH ((T_LEN / L_CHUNK) / ROWS)   // 32
#define N_TILES  ((L_CHUNK + W_WARM) / TS)         // 6 (4 warm, 2 live)

#define WAITVM(n) asm volatile("s_waitcnt vmcnt(" #n ")" ::: "memory")

__device__ __forceinline__ void lds_fence() {
    // orders DS ops (in-order per wave; block = one wave) without draining vmcnt
    asm volatile("s_waitcnt lgkmcnt(0)" ::: "memory");
}

// DMA one 4 KiB tile (64 rows x 16 floats) into LDS; 4 instructions of
// 64 lanes x 16B. Instr i covers rows i*16..i*16+15 (global row stride =
// L_CHUNK=32 floats => per-instr footprint is 16 x 64B segments at 128B
// stride -- strided reads are harmless, granule fills are reused by tile
// t+2 via L2). Lane's slot s = i*64+lane => row l = i*16+(lane>>2),
// logical float4 j = ((lane&3)-(lane>>3))&3 (independent of i).
__device__ __forceinline__ void dma_tile(const float* __restrict__ x,
                                         int base_f, int tile, float* buf)
{
    #pragma unroll
    for (int i = 0; i < 4; ++i) {
        int pos = base_f + i * 512 + tile * TS;   // 16 rows * 32 floats = 512
        pos = pos < 0 ? 0 : pos;     // global block 0 pre-signal clamp (zeroed later)
        __builtin_amdgcn_global_load_lds(
            (__attribute__((address_space(1))) void*)(void*)(x + pos),
            (__attribute__((address_space(3))) void*)(buf + i * 256),
            16, 0, 0);
    }
}

// Process one 16-sample tile for this lane's chunk. zr: zero-fill rows whose
// warm window precedes the channel start (lane 0 tiles 0-3, lane 1 tiles 0-1
// on channel-first blocks).
template <bool WARM>
__device__ __forceinline__ void tile_filter(float* buf, int lane, bool zr,
    float c_b0, float c_b1, float c_b2, float c_a1, float c_a2,
    float& x1, float& x2, float& y1, float& y2)
{
    float4 r[4];
    #pragma unroll
    for (int g = 0; g < 4; ++g)
        r[g] = *(float4*)&buf[(lane * 4 + ((g + (lane >> 1)) & 3)) * 4];

    if (WARM && zr) {
        #pragma unroll
        for (int g = 0; g < 4; ++g) r[g] = make_float4(0.f, 0.f, 0.f, 0.f);
    }

    #pragma unroll
    for (int g = 0; g < 4; ++g) {
        float4 v = r[g];
        float yv;
        yv = c_b0*v.x + c_b1*x1 + c_b2*x2 - c_a1*y1 - c_a2*y2;
        x2 = x1; x1 = v.x; y2 = y1; y1 = yv; v.x = yv;
        yv = c_b0*v.y + c_b1*x1 + c_b2*x2 - c_a1*y1 - c_a2*y2;
        x2 = x1; x1 = v.y; y2 = y1; y1 = yv; v.y = yv;
        yv = c_b0*v.z + c_b1*x1 + c_b2*x2 - c_a1*y1 - c_a2*y2;
        x2 = x1; x1 = v.z; y2 = y1; y1 = yv; v.z = yv;
        yv = c_b0*v.w + c_b1*x1 + c_b2*x2 - c_a1*y1 - c_a2*y2;
        x2 = x1; x1 = v.w; y2 = y1; y1 = yv; v.w = yv;
        if (!WARM) r[g] = v;
    }

    if (!WARM) {         // in-place: staging buffer becomes output buffer
        #pragma unroll
        for (int g = 0; g < 4; ++g)
            *(float4*)&buf[(lane * 4 + ((g + (lane >> 1)) & 3)) * 4] = r[g];
    }
}

__global__ __launch_bounds__(BLK, 5)    // 5 waves/SIMD requested = 20/CU (LDS allows 20)
void hp_biquad_kernel(const float* __restrict__ x, float* __restrict__ y,
                      float c_b0, float c_b1, float c_b2, float c_a1, float c_a2)
{
    __shared__ float bufA[BUF_F];
    __shared__ float bufB[BUF_F];
    const int lane = threadIdx.x;
    const int cg0  = blockIdx.x * ROWS;
    const bool chf = (blockIdx.x & (BLOCKS_PER_CH - 1)) == 0;   // channel-first block

    // per-lane DMA source base (floats): row (lane>>2), permuted float4 j
    const int j0  = ((lane & 3) - (lane >> 3)) & 3;
    const int bsf = (cg0 + (lane >> 2)) * L_CHUNK - W_WARM + j0 * 4;

    float x1 = 0.f, x2 = 0.f, y1 = 0.f, y2 = 0.f;

    // zero-row predicates for warm tiles (channel-first blocks only):
    // garbage iff lane*32 + t*16 < 64  => lane0: t<4, lane1: t<2
    const bool zr01 = chf && (lane < 2);            // tiles 0,1
    const bool zr23 = chf && (lane == 0);           // tiles 2,3

    // ---- 6-tile pipeline (4 warm, 2 live), 2 buffers, counted vmcnt ----
    dma_tile(x, bsf, 0, bufA);                 // out: 4
    dma_tile(x, bsf, 1, bufB);                 // out: 8

    WAITVM(4);                                  // t0 landed
    tile_filter<true>(bufA, lane, zr01, c_b0, c_b1, c_b2, c_a1, c_a2, x1, x2, y1, y2);
    lds_fence();                                // A's reads retired before refill
    dma_tile(x, bsf, 2, bufA);                 // out: <=4(t1) + 4

    WAITVM(4);                                  // t1 landed
    tile_filter<true>(bufB, lane, zr01, c_b0, c_b1, c_b2, c_a1, c_a2, x1, x2, y1, y2);
    lds_fence();
    dma_tile(x, bsf, 3, bufB);                 // out: <=4(t2) + 4

    WAITVM(4);                                  // t2 landed
    tile_filter<true>(bufA, lane, zr23, c_b0, c_b1, c_b2, c_a1, c_a2, x1, x2, y1, y2);
    lds_fence();
    dma_tile(x, bsf, 4, bufA);                 // out: <=4(t3) + 4

    WAITVM(4);                                  // t3 landed
    tile_filter<true>(bufB, lane, zr23, c_b0, c_b1, c_b2, c_a1, c_a2, x1, x2, y1, y2);
    lds_fence();
    dma_tile(x, bsf, 5, bufB);                 // out: <=4(t4) + 4

    WAITVM(4);                                  // t4 landed
    tile_filter<false>(bufA, lane, false, c_b0, c_b1, c_b2, c_a1, c_a2, x1, x2, y1, y2);

    WAITVM(0);                                  // t5 landed
    tile_filter<false>(bufB, lane, false, c_b0, c_b1, c_b2, c_a1, c_a2, x1, x2, y1, y2);
    lds_fence();                                // in-place writes ordered before store reads

    // ---- transposed store: 8 instructions, each 64 lanes x 16B = 1 KiB
    // contiguous; the wave covers an aligned 8 KiB y-region whole => every
    // 512B granule fully dirtied within one back-to-back burst (1x writes).
    // LDS read slot for y-float4 F: chunk c=F>>3, jj=F&7; jj<4 -> bufA
    // (samples 0-15), else bufB; slot = c*4 + (((jj&3)+(c>>1))&3). ----
    const int yb4 = cg0 * (L_CHUNK / 4);        // float4 index base
    #pragma unroll
    for (int k = 0; k < 8; ++k) {
        int c  = k * 8 + (lane >> 3);           // chunk row 0..63
        int jj = lane & 7;
        float* b = (jj < 4) ? bufA : bufB;
        int m  = ((jj & 3) + (c >> 1)) & 3;
        float4 v = *(float4*)&b[(c * 4 + m) * 4];
        *(float4*)(y + 4 * (yb4 + k * 64 + lane)) = v;
    }
}

extern "C" void kernel_launch(void* const* d_in, const int* in_sizes, int n_in,
                              void* d_out, int out_size, void* d_ws, size_t ws_size,
                              hipStream_t stream)
{
    const float* x = (const float*)d_in[0];
    float* y = (float*)d_out;

    // Same double-precision coefficient math as the reference, cast to f32.
    const double SR = 16000.0, FLO = 200.0, FHI = 1200.0;
    const double freq   = 0.5 * (FLO + FHI);      // 700 Hz
    const double cutoff = freq / SR;
    const double q      = 0.70710678;
    const double w0 = 2.0 * M_PI * cutoff;
    const double cw = cos(w0), sw = sin(w0);
    const double alpha = sw / (2.0 * q);
    const double b0 = (1.0 + cw) / 2.0;
    const double b1 = -(1.0 + cw);
    const double b2 = (1.0 + cw) / 2.0;
    const double a0 = 1.0 + alpha;
    const double a1 = -2.0 * cw;
    const double a2 = 1.0 - alpha;
    const float fb0 = (float)(b0 / a0), fb1 = (float)(b1 / a0), fb2 = (float)(b2 / a0);
    const float fa1 = (float)(a1 / a0), fa2 = (float)(a2 / a0);

    const int total  = 128 * 2 * T_LEN;            // 16,777,216 samples
    const int chunks = total / L_CHUNK;            // 524,288
    const int blocks = chunks / ROWS;              // 8192 single-wave blocks

    hp_biquad_kernel<<<blocks, BLK, 0, stream>>>(x, y, fb0, fb1, fb2, fa1, fa2);
    (void)in_sizes; (void)n_in; (void)out_size; (void)d_ws; (void)ws_size;
}

// Round 3
// 116.284 us; speedup vs baseline: 2.0452x; 2.0452x over previous
//
#include <hip/hip_runtime.h>
#include <math.h>

// Biquad highpass IIR over [B=128, C=2, T=65536] f32.
// R7: R4's proven skeleton (the 115us/~29us kernel) with the read side
// improved; revert everything R5/R6 broke.
// Empirical rules from R4-R6 counter evidence:
//   READS:  per-instruction segments must be >=128B contiguous
//           (R6's 64B @128B-stride => FETCH 4.3x; R4/R5 128B segs => ~1x).
//   WRITES: R4's store shape is the only proven-1x one: 16 instrs x 1KB
//           contiguous, terminal, covering an aligned 16KB region/wave at
//           10 blocks/CU (R5 256B pieces => 2.0x; R6 8KB burst @ high
//           occupancy => 6.6x). R7 replicates it exactly.
//   OCCUPANCY: >=10 waves/CU suffices (R6's 42% bought nothing; traffic
//           rules, not latency).
// Delta vs R4: L_CHUNK 64->128, ROWS 64->32 => warm ratio 2.0x -> 1.5x raw
// reads (the main suspect for R4's ~29us vs the 21.3us compulsory floor).
// LDS stays 2 x 8KB, 4096 single-wave blocks, 3-tile pipeline (1 warm,
// 2 live), counted vmcnt(8) waits. DMA segments now 256B @ 512B stride.
// Only lanes 0-31 carry IIR chains (VALU was 6% busy -- irrelevant).
// Numerics: W=64 zero-state warm-up (pole radius 0.8234 => boundary error
// ~4e-6); absmax floor 0.0156 = f32 contraction noise, proven R1-R6.

#define T_LEN    65536
#define L_CHUNK  128
#define W_WARM   64
#define TS       64
#define BLK      64                  // one wave per block
#define ROWS     32                  // chunks per wave
#define BUF_F    (ROWS * TS)         // 2048 floats = 8 KiB per buffer
#define BLOCKS_PER_CH ((T_LEN / L_CHUNK) / ROWS)   // 16

#define WAITVM(n) asm volatile("s_waitcnt vmcnt(" #n ")" ::: "memory")

__device__ __forceinline__ void lds_fence() {
    // orders DS ops (in-order per wave; block = one wave) without draining vmcnt
    asm volatile("s_waitcnt lgkmcnt(0)" ::: "memory");
}

// DMA one 8 KiB tile (32 rows x 64 floats) into LDS; 8 instructions of
// 64 lanes x 16B. Instr i covers rows i*4..i*4+3: per instr 4 x 256B
// contiguous segments at 512B stride (full-line reads, proven clean).
// LDS layout: slot s = r*16 + m holds row r's logical float4
// j = (m - (r&7)) & 15  (rotation spreads compute/store reads over banks).
// Lane mapping: r = i*4 + (lane>>4), m = lane&15 => per-lane global source
// offset j*4 depends only on lane and i-parity (two hoisted bases).
__device__ __forceinline__ void dma_tile(const float* __restrict__ x,
                                         int bE, int bO, int tile, float* buf)
{
    #pragma unroll
    for (int i = 0; i < 8; ++i) {
        int pos = ((i & 1) ? bO : bE) + i * 512 + tile * TS;  // 4 rows*128 = 512
        pos = pos < 0 ? 0 : pos;     // global row 0 pre-signal clamp (zeroed later)
        __builtin_amdgcn_global_load_lds(
            (__attribute__((address_space(1))) void*)(void*)(x + pos),
            (__attribute__((address_space(3))) void*)(buf + i * 256),
            16, 0, 0);
    }
}

// Process one 64-sample tile for this lane's chunk (lanes 0..31 only).
template <bool WARM>
__device__ __forceinline__ void tile_filter(float* buf, int l, bool zr,
    float c_b0, float c_b1, float c_b2, float c_a1, float c_a2,
    float& x1, float& x2, float& y1, float& y2)
{
    float4 r[16];
    #pragma unroll
    for (int j = 0; j < 16; ++j)
        r[j] = *(float4*)&buf[(l * 16 + ((j + (l & 7)) & 15)) * 4];

    if (WARM && zr) {   // channel-start row: pre-channel reads are garbage => state 0
        #pragma unroll
        for (int j = 0; j < 16; ++j) r[j] = make_float4(0.f, 0.f, 0.f, 0.f);
    }

    #pragma unroll
    for (int j = 0; j < 16; ++j) {
        float4 v = r[j];
        float yv;
        yv = c_b0*v.x + c_b1*x1 + c_b2*x2 - c_a1*y1 - c_a2*y2;
        x2 = x1; x1 = v.x; y2 = y1; y1 = yv; v.x = yv;
        yv = c_b0*v.y + c_b1*x1 + c_b2*x2 - c_a1*y1 - c_a2*y2;
        x2 = x1; x1 = v.y; y2 = y1; y1 = yv; v.y = yv;
        yv = c_b0*v.z + c_b1*x1 + c_b2*x2 - c_a1*y1 - c_a2*y2;
        x2 = x1; x1 = v.z; y2 = y1; y1 = yv; v.z = yv;
        yv = c_b0*v.w + c_b1*x1 + c_b2*x2 - c_a1*y1 - c_a2*y2;
        x2 = x1; x1 = v.w; y2 = y1; y1 = yv; v.w = yv;
        if (!WARM) r[j] = v;
    }

    if (!WARM) {         // in-place: staging buffer becomes output buffer
        #pragma unroll
        for (int j = 0; j < 16; ++j)
            *(float4*)&buf[(l * 16 + ((j + (l & 7)) & 15)) * 4] = r[j];
    }
}

__global__ __launch_bounds__(BLK, 4)
void hp_biquad_kernel(const float* __restrict__ x, float* __restrict__ y,
                      float c_b0, float c_b1, float c_b2, float c_a1, float c_a2)
{
    __shared__ float bufA[BUF_F];
    __shared__ float bufB[BUF_F];
    const int lane = threadIdx.x;
    const int cg0  = blockIdx.x * ROWS;
    const bool chf = (blockIdx.x & (BLOCKS_PER_CH - 1)) == 0;   // channel-first block
    const bool zr  = chf && (lane == 0);   // only row 0's warm window precedes channel

    // per-lane DMA source bases: row-quarter rq = lane>>4, permuted float4 j
    // (rotation rot = r&7 = (i&1)*4 + rq  => two bases, even/odd instr)
    const int rq = lane >> 4;
    const int m  = lane & 15;
    const int jE = (m - rq) & 15;
    const int jO = (m - rq - 4) & 15;
    const int rowbase = (cg0 + rq) * L_CHUNK - W_WARM;
    const int bE = rowbase + jE * 4;
    const int bO = rowbase + jO * 4;

    float x1 = 0.f, x2 = 0.f, y1 = 0.f, y2 = 0.f;

    // ---- 3-tile pipeline (t0 warm, t1/t2 live), 2 buffers, counted vmcnt ----
    dma_tile(x, bE, bO, 0, bufA);              // out: 8
    dma_tile(x, bE, bO, 1, bufB);              // out: 16

    WAITVM(8);                                  // t0 landed
    if (lane < ROWS)
        tile_filter<true>(bufA, lane, zr, c_b0, c_b1, c_b2, c_a1, c_a2, x1, x2, y1, y2);
    lds_fence();                                // A's reads retired before refill
    dma_tile(x, bE, bO, 2, bufA);              // out: <=8(t1) + 8

    WAITVM(8);                                  // t1 landed (t2 still in flight)
    if (lane < ROWS)
        tile_filter<false>(bufB, lane, false, c_b0, c_b1, c_b2, c_a1, c_a2, x1, x2, y1, y2);

    WAITVM(0);                                  // t2 landed
    if (lane < ROWS)
        tile_filter<false>(bufA, lane, false, c_b0, c_b1, c_b2, c_a1, c_a2, x1, x2, y1, y2);
    lds_fence();                                // in-place writes ordered before store reads

    // ---- R4-shape store: 16 instructions x 1 KiB contiguous, terminal,
    // covering the wave's aligned 16 KiB y-region whole (proven 1x writes).
    // y float4 q = k*64+lane: chunk c=q>>5, w=q&31; w<16 -> bufB (samples
    // 0-63), else bufA (64-127); slot = c*16 + (((w&15) + (c&7)) & 15). ----
    const int yb4 = cg0 * (L_CHUNK / 4);        // float4 index base = cg0*32
    #pragma unroll
    for (int k = 0; k < 16; ++k) {
        int q  = k * 64 + lane;
        int c  = q >> 5;
        int w  = q & 31;
        float* b = (w < 16) ? bufB : bufA;
        int mm = ((w & 15) + (c & 7)) & 15;
        float4 v = *(float4*)&b[(c * 16 + mm) * 4];
        *(float4*)(y + 4 * (yb4 + q)) = v;
    }
}

extern "C" void kernel_launch(void* const* d_in, const int* in_sizes, int n_in,
                              void* d_out, int out_size, void* d_ws, size_t ws_size,
                              hipStream_t stream)
{
    const float* x = (const float*)d_in[0];
    float* y = (float*)d_out;

    // Same double-precision coefficient math as the reference, cast to f32.
    const double SR = 16000.0, FLO = 200.0, FHI = 1200.0;
    const double freq   = 0.5 * (FLO + FHI);      // 700 Hz
    const double cutoff = freq / SR;
    const double q      = 0.70710678;
    const double w0 = 2.0 * M_PI * cutoff;
    const double cw = cos(w0), sw = sin(w0);
    const double alpha = sw / (2.0 * q);
    const double b0 = (1.0 + cw) / 2.0;
    const double b1 = -(1.0 + cw);
    const double b2 = (1.0 + cw) / 2.0;
    const double a0 = 1.0 + alpha;
    const double a1 = -2.0 * cw;
    const double a2 = 1.0 - alpha;
    const float fb0 = (float)(b0 / a0), fb1 = (float)(b1 / a0), fb2 = (float)(b2 / a0);
    const float fa1 = (float)(a1 / a0), fa2 = (float)(a2 / a0);

    const int total  = 128 * 2 * T_LEN;            // 16,777,216 samples
    const int chunks = total / L_CHUNK;            // 131,072
    const int blocks = chunks / ROWS;              // 4096 single-wave blocks

    hp_biquad_kernel<<<blocks, BLK, 0, stream>>>(x, y, fb0, fb1, fb2, fa1, fa2);
    (void)in_sizes; (void)n_in; (void)out_size; (void)d_ws; (void)ws_size;
}